// Round 1
// baseline (1045.350 us; speedup 1.0000x reference)
//
#include <hip/hip_runtime.h>

#define LAGS 64
#define BATCH 8192
#define XD 128
#define HID 256

typedef unsigned short u16;
typedef unsigned int u32;
typedef unsigned long long u64;
typedef __attribute__((ext_vector_type(8))) short bf16x8;
typedef __attribute__((ext_vector_type(4))) float f32x4;

__device__ __forceinline__ u16 f2b(float f) {
  union { float f; u32 u; } v; v.f = f;
  return (u16)((v.u + 0x7fffu + ((v.u >> 16) & 1u)) >> 16);
}
__device__ __forceinline__ float b2f(u16 h) {
  union { u32 u; float f; } v; v.u = ((u32)h) << 16; return v.f;
}
__device__ __forceinline__ float b2f_lo(u32 u) { union { u32 x; float f; } v; v.x = u << 16; return v.f; }
__device__ __forceinline__ float b2f_hi(u32 u) { union { u32 x; float f; } v; v.x = u & 0xffff0000u; return v.f; }
__device__ __forceinline__ float sigf(float x) { return 1.0f / (1.0f + __expf(-x)); }
__device__ __forceinline__ float tanh_(float x) { float e = __expf(2.0f * x); return 1.0f - 2.0f / (e + 1.0f); }

// ---------------------------------------------------------------------------
// Prologue: build Wcat (bf16, [1024][384], row = h*4+gate; k<256 from W_g, else
// U_g), biasCat[1024], zero C (fp32 [8192][256]) and both H buffers (bf16).
// ---------------------------------------------------------------------------
__global__ void lstm_prep(
    const float* __restrict__ W_f, const float* __restrict__ W_i,
    const float* __restrict__ W_C, const float* __restrict__ W_o,
    const float* __restrict__ U_f, const float* __restrict__ U_i,
    const float* __restrict__ U_C, const float* __restrict__ U_o,
    const float* __restrict__ b_f, const float* __restrict__ b_i,
    const float* __restrict__ b_C, const float* __restrict__ b_o,
    u16* __restrict__ Wcat, float* __restrict__ biasCat,
    float* __restrict__ Ct, u16* __restrict__ H0, u16* __restrict__ H1)
{
  const int gid = blockIdx.x * 256 + threadIdx.x;  // 0..262143
  uint4 z = make_uint4(0, 0, 0, 0);
  ((uint4*)Ct)[gid] = z;
  ((uint4*)Ct)[gid + 262144] = z;
  ((uint4*)H0)[gid] = z;
  ((uint4*)H1)[gid] = z;
  if (gid < 1024) {
    int h = gid >> 2, g = gid & 3;
    const float* B = (g == 0) ? b_f : (g == 1) ? b_i : (g == 2) ? b_C : b_o;
    biasCat[gid] = B[h];
  }
  for (int i = gid; i < 1024 * 384; i += 262144) {
    int row = i / 384, k = i - row * 384;
    int h = row >> 2, g = row & 3;
    float v;
    if (k < 256) {
      const float* P = (g == 0) ? W_f : (g == 1) ? W_i : (g == 2) ? W_C : W_o;
      v = P[k * 256 + h];
    } else {
      const float* P = (g == 0) ? U_f : (g == 1) ? U_i : (g == 2) ? U_C : U_o;
      v = P[(k - 256) * 256 + h];
    }
    Wcat[i] = f2b(v);
  }
}

// ---------------------------------------------------------------------------
// One recurrent step: Z^T[1024][8192] = Wcat @ [Hin; x_t]^T, then gate math.
// Grid (64 n-tiles, 8 m-tiles), 256 threads (4 waves, 2x2), BM=BN=128, BK=64.
// LDS 64 KiB: A dbuf 2x16K at 0, B dbuf 2x16K at 32768. XOR-swizzled k-groups.
// ---------------------------------------------------------------------------
__global__ __launch_bounds__(256, 2) void lstm_step(
    const float* __restrict__ Xt, const u16* __restrict__ Wcat,
    const float* __restrict__ biasCat, const u16* __restrict__ Hin,
    u16* __restrict__ Hout, float* __restrict__ Ct)
{
  __shared__ __align__(16) char smem[65536];
  const int tid = threadIdx.x;
  const int n0 = blockIdx.x * 128;  // batch tile base
  const int m0 = blockIdx.y * 128;  // gate-row tile base
  const int h0 = blockIdx.y * 32;   // hidden-unit tile base

  auto stageA = [&](int buf, int c) {
    char* base = smem + buf * 16384;
#pragma unroll
    for (int i = 0; i < 4; ++i) {
      int idx = tid + i * 256;
      int row = idx >> 3, grp = idx & 7;
      int gk = c * 64 + ((grp ^ (row & 7)) << 3);
      __builtin_amdgcn_global_load_lds(
          (const u32*)(Wcat + (m0 + row) * 384 + gk),
          (u32*)(base + idx * 16), 16, 0, 0);
    }
  };
  auto stageB = [&](int buf, int c) {
    char* base = smem + 32768 + buf * 16384;
    if (c < 4) {
#pragma unroll
      for (int i = 0; i < 4; ++i) {
        int idx = tid + i * 256;
        int bb = idx >> 3, grp = idx & 7;
        int gk = c * 64 + ((grp ^ (bb & 7)) << 3);
        __builtin_amdgcn_global_load_lds(
            (const u32*)(Hin + (size_t)(n0 + bb) * 256 + gk),
            (u32*)(base + idx * 16), 16, 0, 0);
      }
    } else {
      int kbase = (c - 4) * 64;
#pragma unroll
      for (int i = 0; i < 8; ++i) {
        int idx = tid + i * 256;
        int bb = idx >> 4, k4 = idx & 15;
        float4 v = *(const float4*)(Xt + (size_t)(n0 + bb) * 128 + kbase + k4 * 4);
        u32 lo = (u32)f2b(v.x) | ((u32)f2b(v.y) << 16);
        u32 hi = (u32)f2b(v.z) | ((u32)f2b(v.w) << 16);
        int grp = k4 >> 1, half = k4 & 1;
        u32* dst = (u32*)(base + bb * 128 + ((grp ^ (bb & 7)) << 4) + half * 8);
        dst[0] = lo;
        dst[1] = hi;
      }
    }
  };

  f32x4 acc[4][4];
#pragma unroll
  for (int mi = 0; mi < 4; ++mi)
#pragma unroll
    for (int ni = 0; ni < 4; ++ni)
      acc[mi][ni] = (f32x4){0.f, 0.f, 0.f, 0.f};

  const int lane = tid & 63, wid = tid >> 6;
  const int wm = wid >> 1, wn = wid & 1;
  const int lrow = lane & 15, lgrp = lane >> 4;
  const int swz = lrow & 7;

  stageA(0, 0);
  stageB(0, 0);
  __syncthreads();
#pragma unroll
  for (int c = 0; c < 6; ++c) {
    int cur = c & 1;
    if (c < 5) { stageA(cur ^ 1, c + 1); stageB(cur ^ 1, c + 1); }
    const char* Ap = smem + cur * 16384;
    const char* Bp = smem + 32768 + cur * 16384;
#pragma unroll
    for (int kk = 0; kk < 2; ++kk) {
      int koff = ((kk * 4 + lgrp) ^ swz) << 4;
      bf16x8 a[4], b[4];
#pragma unroll
      for (int mi = 0; mi < 4; ++mi)
        a[mi] = *(const bf16x8*)(Ap + (wm * 64 + mi * 16 + lrow) * 128 + koff);
#pragma unroll
      for (int ni = 0; ni < 4; ++ni)
        b[ni] = *(const bf16x8*)(Bp + (wn * 64 + ni * 16 + lrow) * 128 + koff);
#pragma unroll
      for (int mi = 0; mi < 4; ++mi)
#pragma unroll
        for (int ni = 0; ni < 4; ++ni)
          acc[mi][ni] = __builtin_amdgcn_mfma_f32_16x16x32_bf16(a[mi], b[ni], acc[mi][ni], 0, 0, 0);
    }
    __syncthreads();
  }

  // Epilogue: gate math; transpose C/H through LDS for coalesced global I/O.
  float* Cl = (float*)smem;             // [128][36] fp32 (padded)
  u16* Hl = (u16*)(smem + 18432);       // [128][36] bf16 (padded)
#pragma unroll
  for (int i = 0; i < 4; ++i) {
    int idx = tid + i * 256;
    int bb = idx >> 3, h4 = idx & 7;
    float4 v = *(const float4*)(Ct + (size_t)(n0 + bb) * 256 + h0 + h4 * 4);
    *(float4*)(Cl + bb * 36 + h4 * 4) = v;
  }
  __syncthreads();
#pragma unroll
  for (int mi = 0; mi < 4; ++mi) {
    int hl = wm * 16 + mi * 4 + lgrp;  // local h 0..31
    float4 bias = *(const float4*)(biasCat + (size_t)(h0 + hl) * 4);
#pragma unroll
    for (int ni = 0; ni < 4; ++ni) {
      int bl = wn * 64 + ni * 16 + lrow;  // local b 0..127
      float F = sigf(acc[mi][ni][0] + bias.x);
      float I = sigf(acc[mi][ni][1] + bias.y);
      float Cc = tanh_(acc[mi][ni][2] + bias.z);
      float O = sigf(acc[mi][ni][3] + bias.w);
      float Cold = Cl[bl * 36 + hl];
      float Cn = F * Cold + I * Cc;
      Cl[bl * 36 + hl] = Cn;
      Hl[bl * 36 + hl] = f2b(O * tanh_(Cn));
    }
  }
  __syncthreads();
#pragma unroll
  for (int i = 0; i < 4; ++i) {
    int idx = tid + i * 256;
    int bb = idx >> 3, h4 = idx & 7;
    *(float4*)(Ct + (size_t)(n0 + bb) * 256 + h0 + h4 * 4) = *(const float4*)(Cl + bb * 36 + h4 * 4);
    *(u64*)(Hout + (size_t)(n0 + bb) * 256 + h0 + h4 * 4) = *(const u64*)(Hl + bb * 36 + h4 * 4);
  }
}

// ---------------------------------------------------------------------------
// Head: out = tanh((H @ V + bias_out) @ fc1 + fc1_b) @ fc2 + fc2_b
// 256 blocks x 128 threads; each 4-lane group owns one batch row.
// ---------------------------------------------------------------------------
__global__ __launch_bounds__(128) void lstm_head(
    const u16* __restrict__ H, const float* __restrict__ V,
    const float* __restrict__ bias_out, const float* __restrict__ fc1w,
    const float* __restrict__ fc1b, const float* __restrict__ fc2w,
    const float* __restrict__ fc2b, float* __restrict__ out)
{
  __shared__ __align__(16) u16 Vl[256 * 72];
  __shared__ float f1[64 * 64];
  __shared__ float f1b[64], bo[64], f2w_s[192], f2b_s[4];
  const int tid = threadIdx.x;
  for (int i = tid; i < 256 * 64; i += 128) {
    int h = i >> 6, j = i & 63;
    Vl[h * 72 + j] = f2b(V[i]);
  }
  for (int i = tid; i < 4096; i += 128) f1[i] = fc1w[i];
  if (tid < 64) { f1b[tid] = fc1b[tid]; bo[tid] = bias_out[tid]; }
  for (int i = tid; i < 192; i += 128) f2w_s[i] = fc2w[i];
  if (tid < 3) f2b_s[tid] = fc2b[tid];
  __syncthreads();

  const int b = blockIdx.x * 32 + (tid >> 2);
  const int sub = tid & 3;
  float Y[64];
#pragma unroll
  for (int j = 0; j < 64; ++j) Y[j] = 0.f;
  const u16* hrow = H + (size_t)b * 256;
  for (int hh = 0; hh < 64; ++hh) {
    int h = hh * 4 + sub;  // interleaved h split across the 4 lanes of a group
    float hval = b2f(hrow[h]);
    const u16* vr = Vl + h * 72;
#pragma unroll
    for (int jj = 0; jj < 8; ++jj) {
      uint4 vv = *(const uint4*)(vr + jj * 8);
      Y[jj * 8 + 0] += hval * b2f_lo(vv.x);
      Y[jj * 8 + 1] += hval * b2f_hi(vv.x);
      Y[jj * 8 + 2] += hval * b2f_lo(vv.y);
      Y[jj * 8 + 3] += hval * b2f_hi(vv.y);
      Y[jj * 8 + 4] += hval * b2f_lo(vv.z);
      Y[jj * 8 + 5] += hval * b2f_hi(vv.z);
      Y[jj * 8 + 6] += hval * b2f_lo(vv.w);
      Y[jj * 8 + 7] += hval * b2f_hi(vv.w);
    }
  }
#pragma unroll
  for (int j = 0; j < 64; ++j) {
    float y = Y[j];
    y += __shfl_xor(y, 1);
    y += __shfl_xor(y, 2);
    Y[j] = y + bo[j];
  }
  float o0 = 0.f, o1 = 0.f, o2 = 0.f;
  for (int t2 = 0; t2 < 16; ++t2) {
    int j2 = sub * 16 + t2;
    float s = f1b[j2];
#pragma unroll
    for (int j = 0; j < 64; ++j) s += Y[j] * f1[j * 64 + j2];
    float o = tanh_(s);
    o0 += o * f2w_s[j2 * 3 + 0];
    o1 += o * f2w_s[j2 * 3 + 1];
    o2 += o * f2w_s[j2 * 3 + 2];
  }
  o0 += __shfl_xor(o0, 1); o0 += __shfl_xor(o0, 2);
  o1 += __shfl_xor(o1, 1); o1 += __shfl_xor(o1, 2);
  o2 += __shfl_xor(o2, 1); o2 += __shfl_xor(o2, 2);
  if (sub == 0) {
    out[(size_t)b * 3 + 0] = o0 + f2b_s[0];
    out[(size_t)b * 3 + 1] = o1 + f2b_s[1];
    out[(size_t)b * 3 + 2] = o2 + f2b_s[2];
  }
}

extern "C" void kernel_launch(void* const* d_in, const int* in_sizes, int n_in,
                              void* d_out, int out_size, void* d_ws, size_t ws_size,
                              hipStream_t stream) {
  const float* X = (const float*)d_in[0];
  const float* W_f = (const float*)d_in[1];
  const float* W_i = (const float*)d_in[2];
  const float* W_C = (const float*)d_in[3];
  const float* W_o = (const float*)d_in[4];
  const float* U_f = (const float*)d_in[5];
  const float* U_i = (const float*)d_in[6];
  const float* U_C = (const float*)d_in[7];
  const float* U_o = (const float*)d_in[8];
  const float* b_f = (const float*)d_in[9];
  const float* b_i = (const float*)d_in[10];
  const float* b_C = (const float*)d_in[11];
  const float* b_o = (const float*)d_in[12];
  const float* V = (const float*)d_in[13];
  const float* bias_out = (const float*)d_in[14];
  const float* fc1w = (const float*)d_in[15];
  const float* fc1b = (const float*)d_in[16];
  const float* fc2w = (const float*)d_in[17];
  const float* fc2b = (const float*)d_in[18];

  char* ws = (char*)d_ws;
  float* Ct = (float*)(ws);                  // 8 MB
  u16* H0 = (u16*)(ws + 8388608);            // 4 MB
  u16* H1 = (u16*)(ws + 12582912);           // 4 MB
  u16* Wcat = (u16*)(ws + 16777216);         // 768 KB
  float* biasCat = (float*)(ws + 17563648);  // 4 KB

  lstm_prep<<<1024, 256, 0, stream>>>(W_f, W_i, W_C, W_o, U_f, U_i, U_C, U_o,
                                      b_f, b_i, b_C, b_o, Wcat, biasCat, Ct, H0, H1);
  dim3 grid(64, 8);
  for (int t = 0; t < 64; ++t) {
    const u16* Hin = (t & 1) ? H1 : H0;
    u16* Hout = (t & 1) ? H0 : H1;
    lstm_step<<<grid, 256, 0, stream>>>(X + (size_t)t * BATCH * XD, Wcat, biasCat,
                                        Hin, Hout, Ct);
  }
  lstm_head<<<256, 128, 0, stream>>>(H0, V, bias_out, fc1w, fc1b, fc2w, fc2b,
                                     (float*)d_out);
}